// Round 1
// baseline (3296.851 us; speedup 1.0000x reference)
//
#include <hip/hip_runtime.h>
#include <math.h>

// ChamferLoss on MI355X.
// Layout: P = transform(tar) ("points"), Q = transform(fake) ("points_reconstructed").
// out = mean_i min_j |P_i-Q_j|^2 + mean_j min_i |Q_j-P_i|^2  (forward only; argmin
// indices in the reference are only used to gather, so min distance is equivalent).

#define N_PTS 147456   // 384*384
#define IMG_W 384
#define TILE  1024     // per-wave tile edge
#define NT    144      // N_PTS / TILE
#define RI    16       // rows per lane
#define RJ    16       // cols per lane

__device__ __forceinline__ float min3f(float a, float b, float c) {
    float r;
    asm("v_min3_f32 %0, %1, %2, %3" : "=v"(r) : "v"(a), "v"(b), "v"(c));
    return r;
}

// One thread per pixel: spherical depth -> XYZ for BOTH clouds (shared trig),
// plus init of the min buffers (ws is poisoned 0xAA before every launch).
__global__ __launch_bounds__(256) void prep_kernel(
    const float* __restrict__ fake, const float* __restrict__ tar,
    const int* __restrict__ sh_p, const int* __restrict__ sw_p,
    float4* __restrict__ A, float4* __restrict__ B,
    unsigned* __restrict__ minbuf)
{
    int idx = blockIdx.x * 256 + threadIdx.x;
    if (idx >= N_PTS) return;
    int r = idx / IMG_W, c = idx - r * IMG_W;
    int sh = *sh_p, sw = *sw_p;
    // python-double scalars, cast to f32 like JAX weak-type promotion
    float cw = (float)((double)sw / 1285.0 * 360.0);
    float ch = (float)((double)sh / 438.0 * 123.5);
    const float fh = (float)(360.0 * 384.0 / 1285.0);   // fh_crop
    const float fv = (float)(123.5 * 384.0 / 438.0);    // fv_crop
    const float D2R = 0.017453292519943295f;
    float yawdeg = (-fh * (float)c) / 384.0f + cw;
    float pitdeg = (-fv * (float)r) / 384.0f + ch;
    float yaw = yawdeg * D2R, pit = pitdeg * D2R;
    float sy = sinf(yaw), cy = cosf(yaw);
    float sp = sinf(pit), cp = cosf(pit);
    float dt = tar[idx], df = fake[idx];
    A[idx] = make_float4(dt * sy * sp, dt * cy * sp, dt * cp, 0.f);
    B[idx] = make_float4(df * sy * sp, df * cy * sp, df * cp, 0.f);
    minbuf[idx]         = 0x7f800000u;   // +inf bits (rowmin: P->Q)
    minbuf[idx + N_PTS] = 0x7f800000u;   // +inf bits (colmin: Q->P)
}

// Fused NN: per-wave 1024x1024 tile. Each lane: 16 rows (fixed) x 16 cols
// (rotating around the wave ring). Both accumulator sets stay lane-private;
// after 64 rotations the col block+accums return home. atomicMin (uint-punned,
// valid for non-negative IEEE floats) combines partials across tiles.
__global__ __launch_bounds__(256) void nn_kernel(
    const float4* __restrict__ A, const float4* __restrict__ B,
    unsigned* __restrict__ rowmin, unsigned* __restrict__ colmin)
{
    int wave = threadIdx.x >> 6;
    int lane = threadIdx.x & 63;
    int tile = blockIdx.x * 4 + wave;       // 5184 blocks * 4 waves = 20736 tiles
    int ti = tile / NT, tj = tile - ti * NT;
    int rbase = ti * TILE, cbase = tj * TILE;

    float ax[RI], ay[RI], az[RI];
    float bx[RJ], by[RJ], bz[RJ];
    float racc[RI], cacc[RJ];

    #pragma unroll
    for (int k = 0; k < RI; k++) {          // coalesced: row = rbase + k*64 + lane
        float4 p = A[rbase + k * 64 + lane];
        ax[k] = p.x; ay[k] = p.y; az[k] = p.z;
        racc[k] = __builtin_inff();
    }
    #pragma unroll
    for (int m = 0; m < RJ; m++) {          // col block c=lane: col = cbase + m*64 + c
        float4 q = B[cbase + m * 64 + lane];
        bx[m] = q.x; by[m] = q.y; bz[m] = q.z;
        cacc[m] = __builtin_inff();
    }

    int nxt = (lane + 1) & 63;
    #pragma unroll 1
    for (int rr = 0; rr < 64; rr++) {
        #pragma unroll
        for (int k = 0; k < RI; k += 2) {
            #pragma unroll
            for (int m = 0; m < RJ; m += 2) {
                float dx00 = ax[k]   - bx[m],   dy00 = ay[k]   - by[m],   dz00 = az[k]   - bz[m];
                float dx01 = ax[k]   - bx[m+1], dy01 = ay[k]   - by[m+1], dz01 = az[k]   - bz[m+1];
                float dx10 = ax[k+1] - bx[m],   dy10 = ay[k+1] - by[m],   dz10 = az[k+1] - bz[m];
                float dx11 = ax[k+1] - bx[m+1], dy11 = ay[k+1] - by[m+1], dz11 = az[k+1] - bz[m+1];
                float d00 = dx00*dx00 + dy00*dy00 + dz00*dz00;
                float d01 = dx01*dx01 + dy01*dy01 + dz01*dz01;
                float d10 = dx10*dx10 + dy10*dy10 + dz10*dz10;
                float d11 = dx11*dx11 + dy11*dy11 + dz11*dz11;
                racc[k]   = min3f(racc[k],   d00, d01);
                racc[k+1] = min3f(racc[k+1], d10, d11);
                cacc[m]   = min3f(cacc[m],   d00, d10);
                cacc[m+1] = min3f(cacc[m+1], d01, d11);
            }
        }
        // ring-rotate the col block (+ its accumulators) to the previous lane
        #pragma unroll
        for (int m = 0; m < RJ; m++) {
            bx[m]   = __shfl(bx[m],   nxt, 64);
            by[m]   = __shfl(by[m],   nxt, 64);
            bz[m]   = __shfl(bz[m],   nxt, 64);
            cacc[m] = __shfl(cacc[m], nxt, 64);
        }
    }
    // after 64 rotations the block is home: col ids use c = lane
    #pragma unroll
    for (int k = 0; k < RI; k++)
        atomicMin(&rowmin[rbase + k * 64 + lane], __float_as_uint(racc[k]));
    #pragma unroll
    for (int m = 0; m < RJ; m++)
        atomicMin(&colmin[cbase + m * 64 + lane], __float_as_uint(cacc[m]));
}

__global__ __launch_bounds__(256) void reduce1(
    const float* __restrict__ minbuf, float* __restrict__ partials)
{
    int tid = threadIdx.x;
    int base = blockIdx.x * 1024;
    float s = 0.f;
    #pragma unroll
    for (int t = 0; t < 4; t++) s += minbuf[base + t * 256 + tid];
    #pragma unroll
    for (int off = 32; off; off >>= 1) s += __shfl_xor(s, off, 64);
    __shared__ float wsum[4];
    if ((tid & 63) == 0) wsum[tid >> 6] = s;
    __syncthreads();
    if (tid == 0) partials[blockIdx.x] = wsum[0] + wsum[1] + wsum[2] + wsum[3];
}

__global__ __launch_bounds__(256) void reduce2(
    const float* __restrict__ partials, float* __restrict__ out)
{
    int tid = threadIdx.x;
    float s = 0.f;
    for (int i = tid; i < 288; i += 256) s += partials[i];
    #pragma unroll
    for (int off = 32; off; off >>= 1) s += __shfl_xor(s, off, 64);
    __shared__ float wsum[4];
    if ((tid & 63) == 0) wsum[tid >> 6] = s;
    __syncthreads();
    if (tid == 0) out[0] = (wsum[0] + wsum[1] + wsum[2] + wsum[3]) / 147456.0f;
}

extern "C" void kernel_launch(void* const* d_in, const int* in_sizes, int n_in,
                              void* d_out, int out_size, void* d_ws, size_t ws_size,
                              hipStream_t stream) {
    const float* fake = (const float*)d_in[0];
    const float* tar  = (const float*)d_in[1];
    const int*   sh_p = (const int*)d_in[2];
    const int*   sw_p = (const int*)d_in[3];
    float* out = (float*)d_out;

    char* ws = (char*)d_ws;
    float4*   A      = (float4*)ws;                                   // P (tar)  [N]
    float4*   Bc     = (float4*)(ws + (size_t)N_PTS * 16);            // Q (fake) [N]
    unsigned* minbuf = (unsigned*)(ws + (size_t)2 * N_PTS * 16);      // rowmin|colmin [2N]
    float*    parts  = (float*)(ws + (size_t)2 * N_PTS * 16 + (size_t)2 * N_PTS * 4);

    prep_kernel<<<(N_PTS + 255) / 256, 256, 0, stream>>>(fake, tar, sh_p, sw_p, A, Bc, minbuf);
    nn_kernel<<<(NT * NT) / 4, 256, 0, stream>>>(A, Bc, minbuf, minbuf + N_PTS);
    reduce1<<<(2 * N_PTS) / 1024, 256, 0, stream>>>((const float*)minbuf, parts);
    reduce2<<<1, 256, 0, stream>>>(parts, out);
}